// Round 4
// baseline (517.543 us; speedup 1.0000x reference)
//
#include <hip/hip_runtime.h>
#include <math.h>

// Problem constants
constexpr int BB  = 16;
constexpr int CH  = 96;            // CIN == COUT == 96
constexpr int HH  = 96;
constexpr int WW  = 96;
constexpr int HWI = HH * WW;       // 9216
constexpr int CHW = CH * HWI;      // 884736
constexpr int IMG = BB * CHW;      // elems per [B,C,H,W] tensor
constexpr int ATT = BB * CH * CH * 9;  // 1327104 floats
constexpr int WPK = 27 * 6 * 64 * 8;   // 82944 bf16 elems per packed weight matrix

typedef short short8 __attribute__((ext_vector_type(8)));
typedef float floatx4 __attribute__((ext_vector_type(4)));

__device__ __forceinline__ ushort f2bf(float f) {
  union { float f; unsigned u; } v; v.f = f;
  unsigned r = (v.u + 0x7fffu + ((v.u >> 16) & 1u)) >> 16;  // RNE
  return (ushort)r;
}

// ---------------------------------------------------------------------------
// Weight prepack (unchanged): fp32 (m, ci, o) at src[m*864 + ci*9 + o] ->
// bf16 in MFMA A-frag lane order for K ordering k = o*96 + ci, chunks of 32.
// ---------------------------------------------------------------------------
__global__ __launch_bounds__(256) void prepack(
    const float* __restrict__ src, ushort* __restrict__ dst)
{
  const int g = blockIdx.y;
  const int p = blockIdx.x * 256 + threadIdx.x;   // 0..82943
  const float* s = src + (size_t)g * WPK;
  ushort* d = dst + (size_t)g * WPK;
  const int j    = p & 7;
  const int lane = (p >> 3) & 63;
  const int rest = p >> 9;                        // 0..161
  const int mt = rest % 6;
  const int kc = rest / 6;
  const int m  = mt * 16 + (lane & 15);
  const int k  = kc * 32 + (lane >> 4) * 8 + j;
  const int ci = k % 96;
  const int o  = k / 96;
  d[p] = f2bf(s[m * 864 + ci * 9 + o]);
}

// ===========================================================================
// Conv kernels: implicit GEMM, MFMA 16x16x32 bf16. Tile = 6 rows x 32 cols
// (N=192), M=96, K=864 in 27 chunks. Halo 8x34 = 272 px staged in LDS
// [px][ci] (ci-stride 104). 4 waves; wave w owns n-tiles g=3w..3w+2
// (g -> row g>>1, colhalf g&1). bf16 outputs bounce through LDS so global
// stores are contiguous 16B into 64B runs.
// ===========================================================================

// ---- dual: fp32 input x -> Y1,Y2 bf16 ----
__global__ __launch_bounds__(256, 2) void conv_dual_v2(
    const float* __restrict__ X,
    const ushort* __restrict__ WpkA, const ushort* __restrict__ WpkB,
    ushort* __restrict__ YA, ushort* __restrict__ YB)
{
  const int b    = blockIdx.y;
  const int tile = blockIdx.x;
  const int ty0  = (tile / 3) * 6;
  const int tx0  = (tile % 3) * 32;
  const int tid  = threadIdx.x;
  const int lane = tid & 63;
  const int w    = tid >> 6;
  const int nc   = lane & 15;
  const int q    = lane >> 4;

  __shared__ ushort Xs[272 * 104];   // 56,576 B; reused as C-bounce (38,400 B)

  // ---- stage halo tile (16 channels per task => 16 loads in flight) ----
  const float* xb = X + (size_t)b * CHW;
  for (int t = tid; t < 272 * 6; t += 256) {
    const int p  = t % 272;
    const int cg = t / 272;              // channel group of 16
    const int hr = p / 34, hc = p - hr * 34;
    const int gy = ty0 - 1 + hr, gx = tx0 - 1 + hc;
    const bool inb = ((unsigned)gy < 96u) & ((unsigned)gx < 96u);
    const float* s = xb + (size_t)(cg * 16) * HWI + gy * WW + gx;
    ushort u[16];
#pragma unroll
    for (int c = 0; c < 16; ++c) u[c] = inb ? f2bf(s[(size_t)c * HWI]) : (ushort)0;
    ushort* d = &Xs[p * 104 + cg * 16];
#pragma unroll
    for (int v = 0; v < 4; ++v) *(ushort4*)(d + 4 * v) = *(ushort4*)&u[4 * v];
  }
  __syncthreads();

  floatx4 accA[6][3], accB[6][3];
#pragma unroll
  for (int mt = 0; mt < 6; ++mt)
#pragma unroll
    for (int j = 0; j < 3; ++j)
#pragma unroll
      for (int r = 0; r < 4; ++r) { accA[mt][j][r] = 0.f; accB[mt][j][r] = 0.f; }

  for (int o = 0; o < 9; ++o) {
    const int dy = o / 3, dx = o % 3;
#pragma unroll
    for (int cc = 0; cc < 3; ++cc) {
      const int kc  = o * 3 + cc;
      const int cib = cc * 32 + q * 8;

      short8 bfr[3];
#pragma unroll
      for (int j = 0; j < 3; ++j) {
        const int g  = 3 * w + j;
        const int px = ((g >> 1) + dy) * 34 + (g & 1) * 16 + nc + dx;
        bfr[j] = *(const short8*)(&Xs[px * 104 + cib]);
      }

      const size_t abase = (size_t)(kc * 6) * 512 + lane * 8;
      const ushort* apA = WpkA + abase;
      const ushort* apB = WpkB + abase;
#pragma unroll
      for (int mt = 0; mt < 6; ++mt) {
        const short8 afA = *(const short8*)(apA + mt * 512);
#pragma unroll
        for (int j = 0; j < 3; ++j)
          accA[mt][j] = __builtin_amdgcn_mfma_f32_16x16x32_bf16(
              afA, bfr[j], accA[mt][j], 0, 0, 0);
        const short8 afB = *(const short8*)(apB + mt * 512);
#pragma unroll
        for (int j = 0; j < 3; ++j)
          accB[mt][j] = __builtin_amdgcn_mfma_f32_16x16x32_bf16(
              afB, bfr[j], accB[mt][j], 0, 0, 0);
      }
    }
  }

  // ---- bounce epilogue: Cs[co][flatpx], then contiguous 16B stores ----
  ushort* Cs = Xs;
  ushort* const outs[2] = { YA + (size_t)b * CHW, YB + (size_t)b * CHW };
#pragma unroll
  for (int m2 = 0; m2 < 2; ++m2) {
    __syncthreads();
#pragma unroll
    for (int mt = 0; mt < 6; ++mt)
#pragma unroll
      for (int j = 0; j < 3; ++j) {
        const int g  = 3 * w + j;
        const int fp = (g >> 1) * 32 + (g & 1) * 16 + nc;
#pragma unroll
        for (int r = 0; r < 4; ++r) {
          const int co = mt * 16 + q * 4 + r;
          const floatx4& a = m2 ? accB[mt][j] : accA[mt][j];
          Cs[co * 200 + fp] = f2bf(a[r]);
        }
      }
    __syncthreads();
    ushort* yo = outs[m2];
    for (int t = tid; t < 2304; t += 256) {        // 96 co x 24 8-px chunks
      const int co = t / 24, ch = t % 24;
      const int px0 = ch * 8;
      const short8 v = *(const short8*)(&Cs[co * 200 + px0]);
      const int row = px0 >> 5, col = px0 & 31;
      *(short8*)(yo + (size_t)co * HWI + (ty0 + row) * WW + tx0 + col) = v;
    }
  }
}

// ---- single: fp32 input -> bf16 output (conv3) ----
__global__ __launch_bounds__(256, 2) void conv_f2b(
    const float* __restrict__ X, const ushort* __restrict__ Wpk,
    ushort* __restrict__ Y)
{
  const int b    = blockIdx.y;
  const int tile = blockIdx.x;
  const int ty0  = (tile / 3) * 6;
  const int tx0  = (tile % 3) * 32;
  const int tid  = threadIdx.x;
  const int lane = tid & 63;
  const int w    = tid >> 6;
  const int nc   = lane & 15;
  const int q    = lane >> 4;

  __shared__ ushort Xs[272 * 104];

  const float* xb = X + (size_t)b * CHW;
  for (int t = tid; t < 272 * 6; t += 256) {
    const int p  = t % 272;
    const int cg = t / 272;
    const int hr = p / 34, hc = p - hr * 34;
    const int gy = ty0 - 1 + hr, gx = tx0 - 1 + hc;
    const bool inb = ((unsigned)gy < 96u) & ((unsigned)gx < 96u);
    const float* s = xb + (size_t)(cg * 16) * HWI + gy * WW + gx;
    ushort u[16];
#pragma unroll
    for (int c = 0; c < 16; ++c) u[c] = inb ? f2bf(s[(size_t)c * HWI]) : (ushort)0;
    ushort* d = &Xs[p * 104 + cg * 16];
#pragma unroll
    for (int v = 0; v < 4; ++v) *(ushort4*)(d + 4 * v) = *(ushort4*)&u[4 * v];
  }
  __syncthreads();

  floatx4 acc[6][3];
#pragma unroll
  for (int mt = 0; mt < 6; ++mt)
#pragma unroll
    for (int j = 0; j < 3; ++j)
#pragma unroll
      for (int r = 0; r < 4; ++r) acc[mt][j][r] = 0.f;

  for (int o = 0; o < 9; ++o) {
    const int dy = o / 3, dx = o % 3;
#pragma unroll
    for (int cc = 0; cc < 3; ++cc) {
      const int kc  = o * 3 + cc;
      const int cib = cc * 32 + q * 8;
      short8 bfr[3];
#pragma unroll
      for (int j = 0; j < 3; ++j) {
        const int g  = 3 * w + j;
        const int px = ((g >> 1) + dy) * 34 + (g & 1) * 16 + nc + dx;
        bfr[j] = *(const short8*)(&Xs[px * 104 + cib]);
      }
      const ushort* ap = Wpk + (size_t)(kc * 6) * 512 + lane * 8;
#pragma unroll
      for (int mt = 0; mt < 6; ++mt) {
        const short8 af = *(const short8*)(ap + mt * 512);
#pragma unroll
        for (int j = 0; j < 3; ++j)
          acc[mt][j] = __builtin_amdgcn_mfma_f32_16x16x32_bf16(
              af, bfr[j], acc[mt][j], 0, 0, 0);
      }
    }
  }

  __syncthreads();
  ushort* Cs = Xs;
#pragma unroll
  for (int mt = 0; mt < 6; ++mt)
#pragma unroll
    for (int j = 0; j < 3; ++j) {
      const int g  = 3 * w + j;
      const int fp = (g >> 1) * 32 + (g & 1) * 16 + nc;
#pragma unroll
      for (int r = 0; r < 4; ++r)
        Cs[(mt * 16 + q * 4 + r) * 200 + fp] = f2bf(acc[mt][j][r]);
    }
  __syncthreads();
  ushort* yo = Y + (size_t)b * CHW;
  for (int t = tid; t < 2304; t += 256) {
    const int co = t / 24, ch = t % 24;
    const int px0 = ch * 8;
    const short8 v = *(const short8*)(&Cs[co * 200 + px0]);
    const int row = px0 >> 5, col = px0 & 31;
    *(short8*)(yo + (size_t)co * HWI + (ty0 + row) * WW + tx0 + col) = v;
  }
}

// ---- single: bf16 input (Y3) -> fp32 output (d_out), per-batch weights ----
__global__ __launch_bounds__(256, 2) void conv_b2f(
    const ushort* __restrict__ X, const ushort* __restrict__ Wpk,
    float* __restrict__ Y, int wbstride)
{
  const int b    = blockIdx.y;
  const int tile = blockIdx.x;
  const int ty0  = (tile / 3) * 6;
  const int tx0  = (tile % 3) * 32;
  const int tid  = threadIdx.x;
  const int lane = tid & 63;
  const int w    = tid >> 6;
  const int nc   = lane & 15;
  const int q    = lane >> 4;

  __shared__ ushort Xs[272 * 104];

  const ushort* xb = X + (size_t)b * CHW;
  for (int t = tid; t < 272 * 6; t += 256) {
    const int p  = t % 272;
    const int cg = t / 272;
    const int hr = p / 34, hc = p - hr * 34;
    const int gy = ty0 - 1 + hr, gx = tx0 - 1 + hc;
    const bool inb = ((unsigned)gy < 96u) & ((unsigned)gx < 96u);
    const ushort* s = xb + (size_t)(cg * 16) * HWI + gy * WW + gx;
    ushort u[16];
#pragma unroll
    for (int c = 0; c < 16; ++c) u[c] = inb ? s[(size_t)c * HWI] : (ushort)0;
    ushort* d = &Xs[p * 104 + cg * 16];
#pragma unroll
    for (int v = 0; v < 4; ++v) *(ushort4*)(d + 4 * v) = *(ushort4*)&u[4 * v];
  }
  __syncthreads();

  const ushort* wp = Wpk + (size_t)b * wbstride;

  floatx4 acc[6][3];
#pragma unroll
  for (int mt = 0; mt < 6; ++mt)
#pragma unroll
    for (int j = 0; j < 3; ++j)
#pragma unroll
      for (int r = 0; r < 4; ++r) acc[mt][j][r] = 0.f;

  for (int o = 0; o < 9; ++o) {
    const int dy = o / 3, dx = o % 3;
#pragma unroll
    for (int cc = 0; cc < 3; ++cc) {
      const int kc  = o * 3 + cc;
      const int cib = cc * 32 + q * 8;
      short8 bfr[3];
#pragma unroll
      for (int j = 0; j < 3; ++j) {
        const int g  = 3 * w + j;
        const int px = ((g >> 1) + dy) * 34 + (g & 1) * 16 + nc + dx;
        bfr[j] = *(const short8*)(&Xs[px * 104 + cib]);
      }
      const ushort* ap = wp + (size_t)(kc * 6) * 512 + lane * 8;
#pragma unroll
      for (int mt = 0; mt < 6; ++mt) {
        const short8 af = *(const short8*)(ap + mt * 512);
#pragma unroll
        for (int j = 0; j < 3; ++j)
          acc[mt][j] = __builtin_amdgcn_mfma_f32_16x16x32_bf16(
              af, bfr[j], acc[mt][j], 0, 0, 0);
      }
    }
  }

  float* yo = Y + (size_t)b * CHW;
#pragma unroll
  for (int mt = 0; mt < 6; ++mt)
#pragma unroll
    for (int j = 0; j < 3; ++j) {
      const int g  = 3 * w + j;
      const int yy = ty0 + (g >> 1);
      const int xx = tx0 + (g & 1) * 16 + nc;
#pragma unroll
      for (int r = 0; r < 4; ++r) {
        const int co = mt * 16 + q * 4 + r;
        yo[(size_t)co * HWI + yy * WW + xx] = acc[mt][j][r];
      }
    }
}

// ---------------------------------------------------------------------------
// Attention Gram GEMM via MFMA, bf16 inputs (Y1,Y2 already bf16).
// attn[b,k,c,d] = sum_{p in class-k 32x32 grid} Y1[b,c,p] * Y2[b,d,p].
// One block per (b,k); K=1024 in 16 slabs of 64 class-pixels.
// LDS: 2 planes [96][72] bf16 = 27.6 KB. Waves 0..8 compute 2x2 MFMA tiles.
// ---------------------------------------------------------------------------
__global__ __launch_bounds__(1024) void attn_mfma(
    const ushort* __restrict__ Y1, const ushort* __restrict__ Y2,
    float* __restrict__ attnT)
{
  const int b  = blockIdx.x / 9;
  const int k  = blockIdx.x % 9;
  const int kh = k / 3, kw = k % 3;
  const int tid  = threadIdx.x;
  const int lane = tid & 63;
  const int wv   = tid >> 6;          // 0..15

  __shared__ ushort Ah[96 * 72], Bh[96 * 72];

  const ushort* y1b = Y1 + (size_t)b * CHW;
  const ushort* y2b = Y2 + (size_t)b * CHW;

  const int mg = wv / 3;
  const int ng = wv % 3;
  const int cn = lane & 15;
  const int q  = lane >> 4;

  floatx4 acc[2][2];
#pragma unroll
  for (int i = 0; i < 2; ++i)
#pragma unroll
    for (int j = 0; j < 2; ++j)
#pragma unroll
      for (int r = 0; r < 4; ++r) acc[i][j][r] = 0.f;

  const int sj = tid & 31;
  const int sg = tid >> 5;
  const int scol = 3 * sj + kw;

  for (int s = 0; s < 16; ++s) {
    __syncthreads();
#pragma unroll
    for (int c8 = 0; c8 < 3; ++c8) {
      const int c = c8 * 32 + sg;
      const int cbase = c * 72;
#pragma unroll
      for (int ii = 0; ii < 2; ++ii) {
        const int row = 3 * (s * 2 + ii) + kh;
        const int p   = ii * 32 + sj;
        const size_t goff = (size_t)c * HWI + row * WW + scol;
        Ah[cbase + p] = y1b[goff];
        Bh[cbase + p] = y2b[goff];
      }
    }
    __syncthreads();

    if (wv < 9) {
#pragma unroll
      for (int kc = 0; kc < 2; ++kc) {
        short8 ah[2], bh[2];
#pragma unroll
        for (int t = 0; t < 2; ++t) {
          ah[t] = *(const short8*)(&Ah[((mg * 2 + t) * 16 + cn) * 72 + kc * 32 + q * 8]);
          bh[t] = *(const short8*)(&Bh[((ng * 2 + t) * 16 + cn) * 72 + kc * 32 + q * 8]);
        }
#pragma unroll
        for (int i = 0; i < 2; ++i)
#pragma unroll
          for (int j = 0; j < 2; ++j)
            acc[i][j] = __builtin_amdgcn_mfma_f32_16x16x32_bf16(
                ah[i], bh[j], acc[i][j], 0, 0, 0);
      }
    }
  }

  if (wv < 9) {
#pragma unroll
    for (int i = 0; i < 2; ++i)
#pragma unroll
      for (int j = 0; j < 2; ++j)
#pragma unroll
        for (int r = 0; r < 4; ++r) {
          const int c = (mg * 2 + i) * 16 + q * 4 + r;
          const int d = (ng * 2 + j) * 16 + cn;
          attnT[((size_t)(b * CH + d) * CH + c) * 9 + k] = acc[i][j][r];
        }
  }
}

// ---------------------------------------------------------------------------
// Softmax over m = c*9+k (864 values) per (b,d) row (unchanged).
// ---------------------------------------------------------------------------
__global__ __launch_bounds__(256) void softmax_k(
    const float* __restrict__ attnT, float* __restrict__ attnW)
{
  const int bd = blockIdx.x;
  const float* src = attnT + (size_t)bd * 864;
  float* dst = attnW + (size_t)bd * 864;
  const float rs = 0.0340216824f;          // 1/sqrt(864)
  const int tid = threadIdx.x;

  float v0 = src[tid];
  float v1 = src[tid + 256];
  float v2 = src[tid + 512];
  float v3 = (tid < 96) ? src[tid + 768] : -3.0e38f;

  float mx = fmaxf(fmaxf(v0, v1), fmaxf(v2, v3));

  __shared__ float red[256];
  red[tid] = mx;
  __syncthreads();
#pragma unroll
  for (int s = 128; s > 0; s >>= 1) {
    if (tid < s) red[tid] = fmaxf(red[tid], red[tid + s]);
    __syncthreads();
  }
  mx = red[0];
  __syncthreads();

  const float e0 = expf((v0 - mx) * rs);
  const float e1 = expf((v1 - mx) * rs);
  const float e2 = expf((v2 - mx) * rs);
  const float e3 = (tid < 96) ? expf((v3 - mx) * rs) : 0.f;

  red[tid] = e0 + e1 + e2 + e3;
  __syncthreads();
#pragma unroll
  for (int s = 128; s > 0; s >>= 1) {
    if (tid < s) red[tid] += red[tid + s];
    __syncthreads();
  }
  const float inv = 1.f / red[0];

  dst[tid]       = e0 * inv;
  dst[tid + 256] = e1 * inv;
  dst[tid + 512] = e2 * inv;
  if (tid < 96) dst[tid + 768] = e3 * inv;
}

// ---------------------------------------------------------------------------
extern "C" void kernel_launch(void* const* d_in, const int* in_sizes, int n_in,
                              void* d_out, int out_size, void* d_ws, size_t ws_size,
                              hipStream_t stream)
{
  const float* x  = (const float*)d_in[0];
  const float* W1 = (const float*)d_in[1];
  const float* W2 = (const float*)d_in[2];
  const float* W3 = (const float*)d_in[3];

  ushort* Y1   = (ushort*)d_ws;                     // IMG bf16
  ushort* Y2   = Y1 + (size_t)IMG;                  // IMG bf16
  float* attnT = (float*)(Y1 + 2 * (size_t)IMG);    // ATT fp32
  float* attnW = attnT + ATT;                       // ATT fp32
  ushort* pk   = (ushort*)(attnW + ATT);
  ushort* pkW1 = pk;
  ushort* pkW2 = pk + WPK;
  ushort* pkW3 = pk + 2 * (size_t)WPK;
  ushort* pkAW = pk + 3 * (size_t)WPK;              // 16 batch matrices
  ushort* Y3   = Y1;                                // Y1 dead after attn_mfma
  // ws use: 2*IMG*2 + 2*ATT*4 + 19*WPK*2 bytes ~= 70 MB

  const dim3 cgrid(48, BB);                         // 16x3 tiles x batch

  prepack  <<<dim3(324, 1),  256, 0, stream>>>(W1, pkW1);
  prepack  <<<dim3(324, 1),  256, 0, stream>>>(W2, pkW2);
  prepack  <<<dim3(324, 1),  256, 0, stream>>>(W3, pkW3);

  conv_dual_v2<<<cgrid, 256, 0, stream>>>(x, pkW1, pkW2, Y1, Y2);

  attn_mfma<<<BB * 9, 1024, 0, stream>>>(Y1, Y2, attnT);
  softmax_k<<<BB * CH, 256, 0, stream>>>(attnT, attnW);

  prepack  <<<dim3(324, BB), 256, 0, stream>>>(attnW, pkAW);

  conv_f2b <<<cgrid, 256, 0, stream>>>(x, pkW3, Y3);
  conv_b2f <<<cgrid, 256, 0, stream>>>(Y3, pkAW, (float*)d_out, WPK);
}